// Round 1
// baseline (1524.303 us; speedup 1.0000x reference)
//
#include <hip/hip_runtime.h>

#define HG_LEVELS 16
#define HG_TSZ (1u << 19)
#define HG_TMASK (HG_TSZ - 1u)
#define HG_P2 2654435761u
#define HG_P3 805459861u

// resolutions: floor(16 * exp(l * ln(32)/15)) — verified against the double
// rounding chain of the numpy reference (ties-to-even at l*g make all
// power-of-two levels land exactly on the integer).
__device__ __constant__ float kRes[HG_LEVELS] = {
    16.f, 20.f, 25.f, 32.f, 40.f, 50.f, 64.f, 80.f,
    101.f, 128.f, 161.f, 203.f, 256.f, 322.f, 406.f, 512.f};

__global__ __launch_bounds__(256, 4) void hashgrid_fwd(
    const float* __restrict__ coords,   // (n, 3)
    const float* __restrict__ tables,   // (16, 2^19, 2)
    float* __restrict__ out,            // (n, 32)
    int n) {
  // constexpr copy so the unrolled loop folds all per-level constants
  constexpr float RES[HG_LEVELS] = {
      16.f, 20.f, 25.f, 32.f, 40.f, 50.f, 64.f, 80.f,
      101.f, 128.f, 161.f, 203.f, 256.f, 322.f, 406.f, 512.f};

  __shared__ float sout[256 * 33];  // +1 pad per 32-float row: conflict-free

  const int tid = threadIdx.x;
  const int p0 = blockIdx.x << 8;
  const int p = p0 + tid;

  float x = 0.f, y = 0.f, z = 0.f;
  if (p < n) {
    x = coords[3 * p + 0];
    y = coords[3 * p + 1];
    z = coords[3 * p + 2];
  }

#pragma unroll
  for (int l = 0; l < HG_LEVELS; ++l) {
    const float r = RES[l];
    const uint ri = (uint)RES[l];
    const uint rp2 = ri * HG_P2;  // compile-time (mod 2^32)
    const uint rp3 = ri * HG_P3;
    const float2* __restrict__ tb =
        reinterpret_cast<const float2*>(tables) + ((size_t)l << 19);

    const float sx = x * r, sy = y * r, sz = z * r;
    const float fx = floorf(sx), fy = floorf(sy), fz = floorf(sz);
    const float wx = sx - fx, wy = sy - fy, wz = sz - fz;

    // (corner * res) is an exact small integer in fp32; hash in uint32:
    // low 19 bits of the int64 sum == low 19 bits of the uint32 wrap sum.
    const uint hx0 = (uint)(fx * r);
    const uint hx1 = hx0 + ri;
    const uint hy0 = (uint)(fy * r) * HG_P2;
    const uint hy1 = hy0 + rp2;
    const uint hz0 = (uint)(fz * r) * HG_P3;
    const uint hz1 = hz0 + rp3;

    // corner index n = i*4 + j*2 + k  (i->x, j->y, k->z)
    const uint h0 = (hx0 + hy0 + hz0) & HG_TMASK;
    const uint h1 = (hx0 + hy0 + hz1) & HG_TMASK;
    const uint h2 = (hx0 + hy1 + hz0) & HG_TMASK;
    const uint h3 = (hx0 + hy1 + hz1) & HG_TMASK;
    const uint h4 = (hx1 + hy0 + hz0) & HG_TMASK;
    const uint h5 = (hx1 + hy0 + hz1) & HG_TMASK;
    const uint h6 = (hx1 + hy1 + hz0) & HG_TMASK;
    const uint h7 = (hx1 + hy1 + hz1) & HG_TMASK;

    const float2 c0 = tb[h0];
    const float2 c1 = tb[h1];
    const float2 c2 = tb[h2];
    const float2 c3 = tb[h3];
    const float2 c4 = tb[h4];
    const float2 c5 = tb[h5];
    const float2 c6 = tb[h6];
    const float2 c7 = tb[h7];

    const float ox = 1.f - wx, oy = 1.f - wy, oz = 1.f - wz;

    float f0, f1;
    {
      const float c00 = c0.x * ox + c4.x * wx;
      const float c01 = c1.x * ox + c5.x * wx;
      const float c10 = c2.x * ox + c6.x * wx;
      const float c11 = c3.x * ox + c7.x * wx;
      const float d0 = c00 * oy + c10 * wy;
      const float d1 = c01 * oy + c11 * wy;
      f0 = d0 * oz + d1 * wz;
    }
    {
      const float c00 = c0.y * ox + c4.y * wx;
      const float c01 = c1.y * ox + c5.y * wx;
      const float c10 = c2.y * ox + c6.y * wx;
      const float c11 = c3.y * ox + c7.y * wx;
      const float d0 = c00 * oy + c10 * wy;
      const float d1 = c01 * oy + c11 * wy;
      f1 = d0 * oz + d1 * wz;
    }

    sout[tid * 33 + 2 * l + 0] = f0;
    sout[tid * 33 + 2 * l + 1] = f1;
  }

  __syncthreads();

  // coalesced transpose-out: 32 fully-coalesced dword store waves
  const int outbase = p0 * 32;
  const int lim = n * 32;
#pragma unroll
  for (int k = 0; k < 32; ++k) {
    const int flat = (k << 8) + tid;
    const int idx = outbase + flat;
    if (idx < lim) out[idx] = sout[(flat >> 5) * 33 + (flat & 31)];
  }
}

extern "C" void kernel_launch(void* const* d_in, const int* in_sizes, int n_in,
                              void* d_out, int out_size, void* d_ws,
                              size_t ws_size, hipStream_t stream) {
  const float* coords = (const float*)d_in[0];
  const float* tables = (const float*)d_in[1];
  float* out = (float*)d_out;
  const int n = in_sizes[0] / 3;
  const int blocks = (n + 255) / 256;
  hipLaunchKernelGGL(hashgrid_fwd, dim3(blocks), dim3(256), 0, stream,
                     coords, tables, out, n);
}

// Round 2
// 765.443 us; speedup vs baseline: 1.9914x; 1.9914x over previous
//
#include <hip/hip_runtime.h>

#define HG_LEVELS 16
#define HG_TMASK ((1u << 19) - 1u)
#define HG_P2 2654435761u
#define HG_P3 805459861u

// floor(16 * exp(l * ln(32)/15)) — verified against numpy's double rounding.
__device__ __constant__ float kResF[HG_LEVELS] = {
    16.f, 20.f, 25.f, 32.f, 40.f, 50.f, 64.f, 80.f,
    101.f, 128.f, 161.f, 203.f, 256.f, 322.f, 406.f, 512.f};

// ---------------------------------------------------------------------------
// Gather kernel: one (level, point) pair per thread. Level = blockIdx % 8
// (+ lbase) so the round-robin block->XCD dispatch pins each level's 4 MB
// table into exactly one XCD's L2. Two launches (lbase 0, 8) keep the
// per-XCD live working set to ONE table.
// ---------------------------------------------------------------------------
__global__ __launch_bounds__(256) void hg_gather(
    const float* __restrict__ coords,   // (n, 3)
    const float* __restrict__ tables,   // (16, 2^19, 2)
    float2* __restrict__ ws,            // (16, n) feature pairs
    int n, int lbase) {
  const int b = blockIdx.x;
  const int l = lbase + (b & 7);
  const int p = ((b >> 3) << 8) + (int)threadIdx.x;
  if (p >= n) return;

  const float x = coords[3 * p + 0];
  const float y = coords[3 * p + 1];
  const float z = coords[3 * p + 2];

  const float r = kResF[l];
  const uint ri = (uint)r;
  const uint rp2 = ri * HG_P2;  // mod 2^32 wraparound is exact for hash
  const uint rp3 = ri * HG_P3;
  const float2* __restrict__ tb =
      reinterpret_cast<const float2*>(tables) + ((size_t)l << 19);

  const float sx = x * r, sy = y * r, sz = z * r;
  const float fx = floorf(sx), fy = floorf(sy), fz = floorf(sz);
  const float wx = sx - fx, wy = sy - fy, wz = sz - fz;

  // (corner * res) is an exact small integer in fp32; hash entirely in u32:
  // low 19 bits of the int64 sum == low 19 bits of the u32 wraparound sum.
  const uint hx0 = (uint)(fx * r);
  const uint hx1 = hx0 + ri;
  const uint hy0 = (uint)(fy * r) * HG_P2;
  const uint hy1 = hy0 + rp2;
  const uint hz0 = (uint)(fz * r) * HG_P3;
  const uint hz1 = hz0 + rp3;

  const uint h0 = (hx0 + hy0 + hz0) & HG_TMASK;
  const uint h1 = (hx0 + hy0 + hz1) & HG_TMASK;
  const uint h2 = (hx0 + hy1 + hz0) & HG_TMASK;
  const uint h3 = (hx0 + hy1 + hz1) & HG_TMASK;
  const uint h4 = (hx1 + hy0 + hz0) & HG_TMASK;
  const uint h5 = (hx1 + hy0 + hz1) & HG_TMASK;
  const uint h6 = (hx1 + hy1 + hz0) & HG_TMASK;
  const uint h7 = (hx1 + hy1 + hz1) & HG_TMASK;

  const float2 c0 = tb[h0];
  const float2 c1 = tb[h1];
  const float2 c2 = tb[h2];
  const float2 c3 = tb[h3];
  const float2 c4 = tb[h4];
  const float2 c5 = tb[h5];
  const float2 c6 = tb[h6];
  const float2 c7 = tb[h7];

  const float ox = 1.f - wx, oy = 1.f - wy, oz = 1.f - wz;

  float2 f;
  {
    const float c00 = c0.x * ox + c4.x * wx;
    const float c01 = c1.x * ox + c5.x * wx;
    const float c10 = c2.x * ox + c6.x * wx;
    const float c11 = c3.x * ox + c7.x * wx;
    const float d0 = c00 * oy + c10 * wy;
    const float d1 = c01 * oy + c11 * wy;
    f.x = d0 * oz + d1 * wz;
  }
  {
    const float c00 = c0.y * ox + c4.y * wx;
    const float c01 = c1.y * ox + c5.y * wx;
    const float c10 = c2.y * ox + c6.y * wx;
    const float c11 = c3.y * ox + c7.y * wx;
    const float d0 = c00 * oy + c10 * wy;
    const float d1 = c01 * oy + c11 * wy;
    f.y = d0 * oz + d1 * wz;
  }

  ws[l * n + p] = f;  // coalesced: 64 lanes x 8 B contiguous
}

// ---------------------------------------------------------------------------
// Transpose (16, n, 2) ws -> (n, 32) out via padded LDS tile. Pure BW.
// ---------------------------------------------------------------------------
__global__ __launch_bounds__(256, 4) void hg_transpose(
    const float2* __restrict__ ws, float* __restrict__ out, int n) {
  __shared__ float s[256 * 33];
  const int tid = threadIdx.x;
  const int p0 = blockIdx.x << 8;
  const int p = p0 + tid;
  if (p < n) {
#pragma unroll
    for (int l = 0; l < HG_LEVELS; ++l) {
      const float2 v = ws[l * n + p];
      s[tid * 33 + 2 * l + 0] = v.x;
      s[tid * 33 + 2 * l + 1] = v.y;
    }
  }
  __syncthreads();
  const int outbase = p0 * 32;
  const int lim = n * 32;
#pragma unroll
  for (int k = 0; k < 32; ++k) {
    const int flat = (k << 8) + tid;
    const int idx = outbase + flat;
    if (idx < lim) out[idx] = s[(flat >> 5) * 33 + (flat & 31)];
  }
}

// ---------------------------------------------------------------------------
// Fallback (round-1 proven kernel) in case ws_size < 16*n*8 bytes.
// ---------------------------------------------------------------------------
__global__ __launch_bounds__(256, 4) void hashgrid_fwd(
    const float* __restrict__ coords, const float* __restrict__ tables,
    float* __restrict__ out, int n) {
  constexpr float RES[HG_LEVELS] = {
      16.f, 20.f, 25.f, 32.f, 40.f, 50.f, 64.f, 80.f,
      101.f, 128.f, 161.f, 203.f, 256.f, 322.f, 406.f, 512.f};
  __shared__ float sout[256 * 33];
  const int tid = threadIdx.x;
  const int p0 = blockIdx.x << 8;
  const int p = p0 + tid;
  float x = 0.f, y = 0.f, z = 0.f;
  if (p < n) {
    x = coords[3 * p + 0];
    y = coords[3 * p + 1];
    z = coords[3 * p + 2];
  }
#pragma unroll
  for (int l = 0; l < HG_LEVELS; ++l) {
    const float r = RES[l];
    const uint ri = (uint)RES[l];
    const uint rp2 = ri * HG_P2;
    const uint rp3 = ri * HG_P3;
    const float2* __restrict__ tb =
        reinterpret_cast<const float2*>(tables) + ((size_t)l << 19);
    const float sx = x * r, sy = y * r, sz = z * r;
    const float fx = floorf(sx), fy = floorf(sy), fz = floorf(sz);
    const float wx = sx - fx, wy = sy - fy, wz = sz - fz;
    const uint hx0 = (uint)(fx * r);
    const uint hx1 = hx0 + ri;
    const uint hy0 = (uint)(fy * r) * HG_P2;
    const uint hy1 = hy0 + rp2;
    const uint hz0 = (uint)(fz * r) * HG_P3;
    const uint hz1 = hz0 + rp3;
    const float2 c0 = tb[(hx0 + hy0 + hz0) & HG_TMASK];
    const float2 c1 = tb[(hx0 + hy0 + hz1) & HG_TMASK];
    const float2 c2 = tb[(hx0 + hy1 + hz0) & HG_TMASK];
    const float2 c3 = tb[(hx0 + hy1 + hz1) & HG_TMASK];
    const float2 c4 = tb[(hx1 + hy0 + hz0) & HG_TMASK];
    const float2 c5 = tb[(hx1 + hy0 + hz1) & HG_TMASK];
    const float2 c6 = tb[(hx1 + hy1 + hz0) & HG_TMASK];
    const float2 c7 = tb[(hx1 + hy1 + hz1) & HG_TMASK];
    const float ox = 1.f - wx, oy = 1.f - wy, oz = 1.f - wz;
    float f0, f1;
    {
      const float c00 = c0.x * ox + c4.x * wx;
      const float c01 = c1.x * ox + c5.x * wx;
      const float c10 = c2.x * ox + c6.x * wx;
      const float c11 = c3.x * ox + c7.x * wx;
      f0 = (c00 * oy + c10 * wy) * oz + (c01 * oy + c11 * wy) * wz;
    }
    {
      const float c00 = c0.y * ox + c4.y * wx;
      const float c01 = c1.y * ox + c5.y * wx;
      const float c10 = c2.y * ox + c6.y * wx;
      const float c11 = c3.y * ox + c7.y * wx;
      f1 = (c00 * oy + c10 * wy) * oz + (c01 * oy + c11 * wy) * wz;
    }
    sout[tid * 33 + 2 * l + 0] = f0;
    sout[tid * 33 + 2 * l + 1] = f1;
  }
  __syncthreads();
  const int outbase = p0 * 32;
  const int lim = n * 32;
#pragma unroll
  for (int k = 0; k < 32; ++k) {
    const int flat = (k << 8) + tid;
    const int idx = outbase + flat;
    if (idx < lim) out[idx] = sout[(flat >> 5) * 33 + (flat & 31)];
  }
}

extern "C" void kernel_launch(void* const* d_in, const int* in_sizes, int n_in,
                              void* d_out, int out_size, void* d_ws,
                              size_t ws_size, hipStream_t stream) {
  const float* coords = (const float*)d_in[0];
  const float* tables = (const float*)d_in[1];
  float* out = (float*)d_out;
  const int n = in_sizes[0] / 3;
  const int npb = (n + 255) / 256;

  const size_t need = (size_t)HG_LEVELS * (size_t)n * sizeof(float2);
  if (ws_size >= need) {
    float2* ws = (float2*)d_ws;
    // levels 0-7: one table per XCD (all fit a 4 MB L2)
    hipLaunchKernelGGL(hg_gather, dim3(npb * 8), dim3(256), 0, stream,
                       coords, tables, ws, n, 0);
    // levels 8-15: separate launch so an XCD never holds two 4 MB tables
    hipLaunchKernelGGL(hg_gather, dim3(npb * 8), dim3(256), 0, stream,
                       coords, tables, ws, n, 8);
    hipLaunchKernelGGL(hg_transpose, dim3(npb), dim3(256), 0, stream,
                       ws, out, n);
  } else {
    hipLaunchKernelGGL(hashgrid_fwd, dim3(npb), dim3(256), 0, stream,
                       coords, tables, out, n);
  }
}

// Round 4
// 677.846 us; speedup vs baseline: 2.2487x; 1.1292x over previous
//
#include <hip/hip_runtime.h>

#define HG_LEVELS 16
#define HG_M (1u << 19)
#define HG_TMASK (HG_M - 1u)
#define HG_P2 2654435761u
#define HG_P3 805459861u

typedef float f32x2 __attribute__((ext_vector_type(2)));
typedef float f32x4 __attribute__((ext_vector_type(4)));

// floor(16 * exp(l * ln(32)/15)) — verified against numpy's double rounding.
__device__ __constant__ float kResF[HG_LEVELS] = {
    16.f, 20.f, 25.f, 32.f, 40.f, 50.f, 64.f, 80.f,
    101.f, 128.f, 161.f, 203.f, 256.f, 322.f, 406.f, 512.f};

// ---------------------------------------------------------------------------
// Build packed tables: P[l][m] = (T[l][m], T[l][(m + d3) mod M]) as f32x4.
// d3 = (res * P3) mod 2^19 is the constant hash delta between the z=0 and
// z=1 corner of any cell (valid because 2^19 | 2^32). Streaming reads,
// NT streaming writes.
// ---------------------------------------------------------------------------
__global__ __launch_bounds__(256) void hg_build(
    const float* __restrict__ tables, f32x4* __restrict__ packed) {
  const int l = blockIdx.x >> 11;  // 2048 blocks/level
  const uint m = ((blockIdx.x & 2047u) << 8) | threadIdx.x;
  const uint ri = (uint)kResF[l];
  const uint d3 = (ri * HG_P3) & HG_TMASK;
  const f32x2* __restrict__ tb =
      reinterpret_cast<const f32x2*>(tables) + ((size_t)l << 19);
  const f32x2 a = tb[m];
  const f32x2 b = tb[(m + d3) & HG_TMASK];
  f32x4 v;
  v.x = a.x; v.y = a.y; v.z = b.x; v.w = b.y;
  __builtin_nontemporal_store(v, &packed[((size_t)l << 19) + m]);
}

// ---------------------------------------------------------------------------
// Gather with packed tables: 4 x dwordx4 per (point, level) instead of
// 8 x dwordx2. Level = lbase + blockIdx%8 pins one packed table per XCD.
// ---------------------------------------------------------------------------
__global__ __launch_bounds__(256) void hg_gather_p(
    const float* __restrict__ coords, const f32x4* __restrict__ packed,
    f32x2* __restrict__ feats, int n, int lbase) {
  const int b = blockIdx.x;
  const int l = lbase + (b & 7);
  const int p = ((b >> 3) << 8) + (int)threadIdx.x;
  if (p >= n) return;

  const float x = coords[3 * p + 0];
  const float y = coords[3 * p + 1];
  const float z = coords[3 * p + 2];

  const float r = kResF[l];
  const uint ri = (uint)r;
  const uint rp2 = ri * HG_P2;
  const f32x4* __restrict__ tb = packed + ((size_t)l << 19);

  const float sx = x * r, sy = y * r, sz = z * r;
  const float fx = floorf(sx), fy = floorf(sy), fz = floorf(sz);
  const float wx = sx - fx, wy = sy - fy, wz = sz - fz;

  // exact u32 hash (low 19 bits of the int64 sum == u32 wraparound sum)
  const uint hx0 = (uint)(fx * r);
  const uint hy0 = (uint)(fy * r) * HG_P2;
  const uint hz0 = (uint)(fz * r) * HG_P3;
  const uint base = hx0 + hy0 + hz0;

  const uint m00 = base & HG_TMASK;               // (x0,y0) -> c0,c1
  const uint m01 = (base + rp2) & HG_TMASK;       // (x0,y1) -> c2,c3
  const uint m10 = (base + ri) & HG_TMASK;        // (x1,y0) -> c4,c5
  const uint m11 = (base + ri + rp2) & HG_TMASK;  // (x1,y1) -> c6,c7

  const f32x4 q00 = tb[m00];
  const f32x4 q01 = tb[m01];
  const f32x4 q10 = tb[m10];
  const f32x4 q11 = tb[m11];

  const float ox = 1.f - wx, oy = 1.f - wy, oz = 1.f - wz;

  f32x2 f;
  {
    const float c00 = q00.x * ox + q10.x * wx;
    const float c01 = q00.z * ox + q10.z * wx;
    const float c10 = q01.x * ox + q11.x * wx;
    const float c11 = q01.z * ox + q11.z * wx;
    f.x = (c00 * oy + c10 * wy) * oz + (c01 * oy + c11 * wy) * wz;
  }
  {
    const float c00 = q00.y * ox + q10.y * wx;
    const float c01 = q00.w * ox + q10.w * wx;
    const float c10 = q01.y * ox + q11.y * wx;
    const float c11 = q01.w * ox + q11.w * wx;
    f.y = (c00 * oy + c10 * wy) * oz + (c01 * oy + c11 * wy) * wz;
  }

  // NT store: never re-read through L2 (transpose pulls from L3 clean)
  __builtin_nontemporal_store(f, &feats[(size_t)l * n + p]);
}

// ---------------------------------------------------------------------------
// Transpose (16, n, 2) feats -> (n, 32) out via padded LDS tile. NT loads
// (read-once) + NT stores (write-once).
// ---------------------------------------------------------------------------
__global__ __launch_bounds__(256, 4) void hg_transpose(
    const f32x2* __restrict__ feats, float* __restrict__ out, int n) {
  __shared__ float s[256 * 33];
  const int tid = threadIdx.x;
  const int p0 = blockIdx.x << 8;
  const int p = p0 + tid;
  if (p < n) {
#pragma unroll
    for (int l = 0; l < HG_LEVELS; ++l) {
      const f32x2 v = __builtin_nontemporal_load(&feats[(size_t)l * n + p]);
      s[tid * 33 + 2 * l + 0] = v.x;
      s[tid * 33 + 2 * l + 1] = v.y;
    }
  }
  __syncthreads();
  const int outbase = p0 * 32;
  const int lim = n * 32;
#pragma unroll
  for (int k = 0; k < 32; ++k) {
    const int flat = (k << 8) + tid;
    const int idx = outbase + flat;
    if (idx < lim)
      __builtin_nontemporal_store(s[(flat >> 5) * 33 + (flat & 31)],
                                  &out[idx]);
  }
}

// ---------------------------------------------------------------------------
// Tier-B fallback: round-2 unpacked gather (proven, 765 us total path).
// ---------------------------------------------------------------------------
__global__ __launch_bounds__(256) void hg_gather(
    const float* __restrict__ coords, const float* __restrict__ tables,
    f32x2* __restrict__ ws, int n, int lbase) {
  const int b = blockIdx.x;
  const int l = lbase + (b & 7);
  const int p = ((b >> 3) << 8) + (int)threadIdx.x;
  if (p >= n) return;
  const float x = coords[3 * p + 0];
  const float y = coords[3 * p + 1];
  const float z = coords[3 * p + 2];
  const float r = kResF[l];
  const uint ri = (uint)r;
  const uint rp2 = ri * HG_P2;
  const uint rp3 = ri * HG_P3;
  const f32x2* __restrict__ tb =
      reinterpret_cast<const f32x2*>(tables) + ((size_t)l << 19);
  const float sx = x * r, sy = y * r, sz = z * r;
  const float fx = floorf(sx), fy = floorf(sy), fz = floorf(sz);
  const float wx = sx - fx, wy = sy - fy, wz = sz - fz;
  const uint hx0 = (uint)(fx * r);
  const uint hx1 = hx0 + ri;
  const uint hy0 = (uint)(fy * r) * HG_P2;
  const uint hy1 = hy0 + rp2;
  const uint hz0 = (uint)(fz * r) * HG_P3;
  const uint hz1 = hz0 + rp3;
  const f32x2 c0 = tb[(hx0 + hy0 + hz0) & HG_TMASK];
  const f32x2 c1 = tb[(hx0 + hy0 + hz1) & HG_TMASK];
  const f32x2 c2 = tb[(hx0 + hy1 + hz0) & HG_TMASK];
  const f32x2 c3 = tb[(hx0 + hy1 + hz1) & HG_TMASK];
  const f32x2 c4 = tb[(hx1 + hy0 + hz0) & HG_TMASK];
  const f32x2 c5 = tb[(hx1 + hy0 + hz1) & HG_TMASK];
  const f32x2 c6 = tb[(hx1 + hy1 + hz0) & HG_TMASK];
  const f32x2 c7 = tb[(hx1 + hy1 + hz1) & HG_TMASK];
  const float ox = 1.f - wx, oy = 1.f - wy, oz = 1.f - wz;
  f32x2 f;
  {
    const float c00 = c0.x * ox + c4.x * wx;
    const float c01 = c1.x * ox + c5.x * wx;
    const float c10 = c2.x * ox + c6.x * wx;
    const float c11 = c3.x * ox + c7.x * wx;
    f.x = (c00 * oy + c10 * wy) * oz + (c01 * oy + c11 * wy) * wz;
  }
  {
    const float c00 = c0.y * ox + c4.y * wx;
    const float c01 = c1.y * ox + c5.y * wx;
    const float c10 = c2.y * ox + c6.y * wx;
    const float c11 = c3.y * ox + c7.y * wx;
    f.y = (c00 * oy + c10 * wy) * oz + (c01 * oy + c11 * wy) * wz;
  }
  __builtin_nontemporal_store(f, &ws[(size_t)l * n + p]);
}

// ---------------------------------------------------------------------------
// Tier-C fallback: monolithic round-1 kernel (no ws needed).
// ---------------------------------------------------------------------------
__global__ __launch_bounds__(256, 4) void hashgrid_fwd(
    const float* __restrict__ coords, const float* __restrict__ tables,
    float* __restrict__ out, int n) {
  constexpr float RES[HG_LEVELS] = {
      16.f, 20.f, 25.f, 32.f, 40.f, 50.f, 64.f, 80.f,
      101.f, 128.f, 161.f, 203.f, 256.f, 322.f, 406.f, 512.f};
  __shared__ float sout[256 * 33];
  const int tid = threadIdx.x;
  const int p0 = blockIdx.x << 8;
  const int p = p0 + tid;
  float x = 0.f, y = 0.f, z = 0.f;
  if (p < n) {
    x = coords[3 * p + 0];
    y = coords[3 * p + 1];
    z = coords[3 * p + 2];
  }
#pragma unroll
  for (int l = 0; l < HG_LEVELS; ++l) {
    const float r = RES[l];
    const uint ri = (uint)RES[l];
    const uint rp2 = ri * HG_P2;
    const uint rp3 = ri * HG_P3;
    const f32x2* __restrict__ tb =
        reinterpret_cast<const f32x2*>(tables) + ((size_t)l << 19);
    const float sx = x * r, sy = y * r, sz = z * r;
    const float fx = floorf(sx), fy = floorf(sy), fz = floorf(sz);
    const float wx = sx - fx, wy = sy - fy, wz = sz - fz;
    const uint hx0 = (uint)(fx * r);
    const uint hx1 = hx0 + ri;
    const uint hy0 = (uint)(fy * r) * HG_P2;
    const uint hy1 = hy0 + rp2;
    const uint hz0 = (uint)(fz * r) * HG_P3;
    const uint hz1 = hz0 + rp3;
    const f32x2 c0 = tb[(hx0 + hy0 + hz0) & HG_TMASK];
    const f32x2 c1 = tb[(hx0 + hy0 + hz1) & HG_TMASK];
    const f32x2 c2 = tb[(hx0 + hy1 + hz0) & HG_TMASK];
    const f32x2 c3 = tb[(hx0 + hy1 + hz1) & HG_TMASK];
    const f32x2 c4 = tb[(hx1 + hy0 + hz0) & HG_TMASK];
    const f32x2 c5 = tb[(hx1 + hy0 + hz1) & HG_TMASK];
    const f32x2 c6 = tb[(hx1 + hy1 + hz0) & HG_TMASK];
    const f32x2 c7 = tb[(hx1 + hy1 + hz1) & HG_TMASK];
    const float ox = 1.f - wx, oy = 1.f - wy, oz = 1.f - wz;
    float f0, f1;
    {
      const float c00 = c0.x * ox + c4.x * wx;
      const float c01 = c1.x * ox + c5.x * wx;
      const float c10 = c2.x * ox + c6.x * wx;
      const float c11 = c3.x * ox + c7.x * wx;
      f0 = (c00 * oy + c10 * wy) * oz + (c01 * oy + c11 * wy) * wz;
    }
    {
      const float c00 = c0.y * ox + c4.y * wx;
      const float c01 = c1.y * ox + c5.y * wx;
      const float c10 = c2.y * ox + c6.y * wx;
      const float c11 = c3.y * ox + c7.y * wx;
      f1 = (c00 * oy + c10 * wy) * oz + (c01 * oy + c11 * wy) * wz;
    }
    sout[tid * 33 + 2 * l + 0] = f0;
    sout[tid * 33 + 2 * l + 1] = f1;
  }
  __syncthreads();
  const int outbase = p0 * 32;
  const int lim = n * 32;
#pragma unroll
  for (int k = 0; k < 32; ++k) {
    const int flat = (k << 8) + tid;
    const int idx = outbase + flat;
    if (idx < lim) out[idx] = sout[(flat >> 5) * 33 + (flat & 31)];
  }
}

extern "C" void kernel_launch(void* const* d_in, const int* in_sizes, int n_in,
                              void* d_out, int out_size, void* d_ws,
                              size_t ws_size, hipStream_t stream) {
  const float* coords = (const float*)d_in[0];
  const float* tables = (const float*)d_in[1];
  float* out = (float*)d_out;
  const int n = in_sizes[0] / 3;
  const int npb = (n + 255) / 256;

  const size_t packed_bytes = (size_t)HG_LEVELS * HG_M * sizeof(f32x4);
  const size_t feat_bytes = (size_t)HG_LEVELS * (size_t)n * sizeof(f32x2);

  if (ws_size >= packed_bytes + feat_bytes) {
    // Tier A: packed z-pair tables (4 x 16 B gathers per point-level)
    f32x4* packed = (f32x4*)d_ws;
    f32x2* feats = (f32x2*)((char*)d_ws + packed_bytes);
    hipLaunchKernelGGL(hg_build, dim3(HG_LEVELS * 2048), dim3(256), 0, stream,
                       tables, packed);
    hipLaunchKernelGGL(hg_gather_p, dim3(npb * 8), dim3(256), 0, stream,
                       coords, packed, feats, n, 0);
    hipLaunchKernelGGL(hg_gather_p, dim3(npb * 8), dim3(256), 0, stream,
                       coords, packed, feats, n, 8);
    hipLaunchKernelGGL(hg_transpose, dim3(npb), dim3(256), 0, stream,
                       feats, out, n);
  } else if (ws_size >= feat_bytes) {
    // Tier B: round-2 proven path
    f32x2* feats = (f32x2*)d_ws;
    hipLaunchKernelGGL(hg_gather, dim3(npb * 8), dim3(256), 0, stream,
                       coords, tables, feats, n, 0);
    hipLaunchKernelGGL(hg_gather, dim3(npb * 8), dim3(256), 0, stream,
                       coords, tables, feats, n, 8);
    hipLaunchKernelGGL(hg_transpose, dim3(npb), dim3(256), 0, stream,
                       feats, out, n);
  } else {
    // Tier C: monolithic
    hipLaunchKernelGGL(hashgrid_fwd, dim3(npb), dim3(256), 0, stream,
                       coords, tables, out, n);
  }
}